// Round 1
// baseline (2822.902 us; speedup 1.0000x reference)
//
#include <hip/hip_runtime.h>

#define N_NODES 1024
#define E_EDGES 524288
#define FE 64
#define FC 128
#define NLAYERS 3

// ---------------------------------------------------------------------------
// Node projections: f_ni = node@W_ni, f_nj = node@W_nj, h = node@W_node + bias
// One block per node. Threads 0-63 -> f_ni, 64-127 -> f_nj, 128-255 -> h.
// Also resets z[d] = 0 for the softmax denominator.
// ---------------------------------------------------------------------------
__global__ __launch_bounds__(256) void node_kernel(
    const float* __restrict__ node,
    const float* __restrict__ Wni, const float* __restrict__ Wnj,
    const float* __restrict__ Wnode, const float* __restrict__ bias,
    float* __restrict__ fni, float* __restrict__ fnj,
    float* __restrict__ h, float* __restrict__ z)
{
    __shared__ float row[FC];
    const int d = blockIdx.x;
    if (threadIdx.x < FC) row[threadIdx.x] = node[d * FC + threadIdx.x];
    if (threadIdx.x == 0) z[d] = 0.f;
    __syncthreads();

    const int t = threadIdx.x;
    if (t < 64) {
        float a = 0.f;
        #pragma unroll 8
        for (int k = 0; k < FC; k++) a = fmaf(row[k], Wni[k * FE + t], a);
        fni[d * FE + t] = a;
    } else if (t < 128) {
        const int f = t - 64;
        float a = 0.f;
        #pragma unroll 8
        for (int k = 0; k < FC; k++) a = fmaf(row[k], Wnj[k * FE + f], a);
        fnj[d * FE + f] = a;
    } else {
        const int c = t - 128;
        float a = bias[c];
        #pragma unroll 8
        for (int k = 0; k < FC; k++) a = fmaf(row[k], Wnode[k * FC + c], a);
        h[d * FC + c] = a;
    }
}

// ---------------------------------------------------------------------------
// Fused edge kernel. For each edge e:
//   f_out = leaky_relu(f_ni[src] + f_nj[dst] + ef@W_fij, 0.2)
//   ef    = ef + f_out            (in place; for FIRST layer ef is computed
//                                  on the fly from edge_feature@W_in + b_in)
//   p[e]  = exp(f_out . attn)     (softmax without max-shift: logits bounded)
//   z[dst] += p[e]                (atomic)
// 16 lanes per edge, 4 edges register-blocked per group. W_fij in LDS.
// ---------------------------------------------------------------------------
template <bool FIRST>
__global__ __launch_bounds__(256) void edge_kernel(
    float* __restrict__ ef,
    const float* __restrict__ x,          // edge_feature [E][2]  (FIRST only)
    const float* __restrict__ Win,        // [2][64]              (FIRST only)
    const float* __restrict__ bin,        // [64]                 (FIRST only)
    const float* __restrict__ fni, const float* __restrict__ fnj,
    const int* __restrict__ src, const int* __restrict__ dst,
    const float* __restrict__ Wfij,       // [64][64]
    const float* __restrict__ attn,       // [64]
    float* __restrict__ p, float* __restrict__ z)
{
    __shared__ float Wl[FE * FE];
    __shared__ float al[FE];
    __shared__ float w0l[FE], w1l[FE], bl[FE];
    for (int i = threadIdx.x; i < FE * FE; i += 256) Wl[i] = Wfij[i];
    if (threadIdx.x < FE) {
        al[threadIdx.x] = attn[threadIdx.x];
        if (FIRST) {
            w0l[threadIdx.x] = Win[threadIdx.x];
            w1l[threadIdx.x] = Win[FE + threadIdx.x];
            bl[threadIdx.x]  = bin[threadIdx.x];
        }
    }
    __syncthreads();

    const int lane = threadIdx.x & 15;
    const int group = (blockIdx.x * 256 + threadIdx.x) >> 4;
    const int ngroups = (gridDim.x * 256) >> 4;

    for (int tile = group * 4; tile < E_EDGES; tile += ngroups * 4) {
        float4 efv[4], acc[4];
        int d4[4];
        #pragma unroll
        for (int t = 0; t < 4; t++) {
            const int e = tile + t;
            if (FIRST) {
                const float x0 = x[e * 2], x1 = x[e * 2 + 1];
                efv[t].x = fmaf(x0, w0l[lane*4+0], fmaf(x1, w1l[lane*4+0], bl[lane*4+0]));
                efv[t].y = fmaf(x0, w0l[lane*4+1], fmaf(x1, w1l[lane*4+1], bl[lane*4+1]));
                efv[t].z = fmaf(x0, w0l[lane*4+2], fmaf(x1, w1l[lane*4+2], bl[lane*4+2]));
                efv[t].w = fmaf(x0, w0l[lane*4+3], fmaf(x1, w1l[lane*4+3], bl[lane*4+3]));
            } else {
                efv[t] = *reinterpret_cast<const float4*>(ef + (size_t)e * FE + lane * 4);
            }
            const int s = src[e];
            d4[t] = dst[e];
            const float4 a = *reinterpret_cast<const float4*>(fni + s * FE + lane * 4);
            const float4 b = *reinterpret_cast<const float4*>(fnj + d4[t] * FE + lane * 4);
            acc[t] = make_float4(a.x + b.x, a.y + b.y, a.z + b.z, a.w + b.w);
        }
        // acc[t][f] += sum_k efv[k] * W[k][f],  f = lane*4 .. lane*4+3
        #pragma unroll
        for (int k4 = 0; k4 < 16; k4++) {
            const float4 w0 = *reinterpret_cast<const float4*>(&Wl[(k4*4+0)*FE + lane*4]);
            const float4 w1 = *reinterpret_cast<const float4*>(&Wl[(k4*4+1)*FE + lane*4]);
            const float4 w2 = *reinterpret_cast<const float4*>(&Wl[(k4*4+2)*FE + lane*4]);
            const float4 w3 = *reinterpret_cast<const float4*>(&Wl[(k4*4+3)*FE + lane*4]);
            #pragma unroll
            for (int t = 0; t < 4; t++) {
                const float e0 = __shfl(efv[t].x, k4, 16);
                const float e1 = __shfl(efv[t].y, k4, 16);
                const float e2 = __shfl(efv[t].z, k4, 16);
                const float e3 = __shfl(efv[t].w, k4, 16);
                acc[t].x = fmaf(e0, w0.x, acc[t].x); acc[t].y = fmaf(e0, w0.y, acc[t].y);
                acc[t].z = fmaf(e0, w0.z, acc[t].z); acc[t].w = fmaf(e0, w0.w, acc[t].w);
                acc[t].x = fmaf(e1, w1.x, acc[t].x); acc[t].y = fmaf(e1, w1.y, acc[t].y);
                acc[t].z = fmaf(e1, w1.z, acc[t].z); acc[t].w = fmaf(e1, w1.w, acc[t].w);
                acc[t].x = fmaf(e2, w2.x, acc[t].x); acc[t].y = fmaf(e2, w2.y, acc[t].y);
                acc[t].z = fmaf(e2, w2.z, acc[t].z); acc[t].w = fmaf(e2, w2.w, acc[t].w);
                acc[t].x = fmaf(e3, w3.x, acc[t].x); acc[t].y = fmaf(e3, w3.y, acc[t].y);
                acc[t].z = fmaf(e3, w3.z, acc[t].z); acc[t].w = fmaf(e3, w3.w, acc[t].w);
            }
        }
        float pv[4];
        const float4 av = *reinterpret_cast<const float4*>(&al[lane * 4]);
        #pragma unroll
        for (int t = 0; t < 4; t++) {
            float4 f;
            f.x = acc[t].x > 0.f ? acc[t].x : 0.2f * acc[t].x;
            f.y = acc[t].y > 0.f ? acc[t].y : 0.2f * acc[t].y;
            f.z = acc[t].z > 0.f ? acc[t].z : 0.2f * acc[t].z;
            f.w = acc[t].w > 0.f ? acc[t].w : 0.2f * acc[t].w;
            // ef update
            const float4 outv = make_float4(efv[t].x + f.x, efv[t].y + f.y,
                                            efv[t].z + f.z, efv[t].w + f.w);
            *reinterpret_cast<float4*>(ef + (size_t)(tile + t) * FE + lane * 4) = outv;
            // logit partial + 16-lane reduce
            float part = f.x * av.x + f.y * av.y + f.z * av.z + f.w * av.w;
            part += __shfl_xor(part, 1, 16);
            part += __shfl_xor(part, 2, 16);
            part += __shfl_xor(part, 4, 16);
            part += __shfl_xor(part, 8, 16);
            pv[t] = expf(part);
        }
        if (lane == 0) {
            #pragma unroll
            for (int t = 0; t < 4; t++) {
                p[tile + t] = pv[t];
                atomicAdd(z + d4[t], pv[t]);
            }
        }
    }
}

// ---------------------------------------------------------------------------
// a[e] = p[e] / z[dst[e]]; scatter into dense S[dst][src] += a
// ---------------------------------------------------------------------------
__global__ __launch_bounds__(256) void scatter_kernel(
    const float* __restrict__ p, const float* __restrict__ z,
    const int* __restrict__ src, const int* __restrict__ dst,
    float* __restrict__ S)
{
    const int e = blockIdx.x * 256 + threadIdx.x;
    if (e < E_EDGES) {
        const int d = dst[e];
        const float a = p[e] / z[d];
        atomicAdd(S + (size_t)d * N_NODES + src[e], a);
    }
}

// ---------------------------------------------------------------------------
// node_out = node_in + S @ h.   One block per dst row; half-block splits the
// n-dimension, LDS reduce at the end.
// ---------------------------------------------------------------------------
__global__ __launch_bounds__(256) void spmm_kernel(
    const float* __restrict__ S, const float* __restrict__ h,
    const float* __restrict__ nin, float* __restrict__ nout)
{
    __shared__ float red[256];
    const int d = blockIdx.x;
    const int c = threadIdx.x & 127;
    const int half = threadIdx.x >> 7;
    const float* Srow = S + (size_t)d * N_NODES + half * 512;
    const float* hp = h + (size_t)half * 512 * FC;
    float acc = 0.f;
    #pragma unroll 8
    for (int n = 0; n < 512; n++) {
        acc = fmaf(Srow[n], hp[n * FC + c], acc);
    }
    red[threadIdx.x] = acc;
    __syncthreads();
    if (half == 0) {
        nout[d * FC + c] = nin[d * FC + c] + red[c] + red[128 + c];
    }
}

// ---------------------------------------------------------------------------
extern "C" void kernel_launch(void* const* d_in, const int* in_sizes, int n_in,
                              void* d_out, int out_size, void* d_ws, size_t ws_size,
                              hipStream_t stream)
{
    const float* node_feature = (const float*)d_in[0];
    const float* edge_feature = (const float*)d_in[1];
    const int*   src          = (const int*)d_in[2];
    const int*   dst          = (const int*)d_in[3];
    const float* W_in         = (const float*)d_in[4];
    const float* b_in         = (const float*)d_in[5];
    const float* W_ni         = (const float*)d_in[6];
    const float* W_nj         = (const float*)d_in[7];
    const float* W_fij        = (const float*)d_in[8];
    const float* W_node       = (const float*)d_in[9];
    const float* attn         = (const float*)d_in[10];
    const float* bias_node    = (const float*)d_in[11];
    float* out = (float*)d_out;

    char* ws = (char*)d_ws;
    size_t off = 0;
    auto alloc = [&](size_t bytes) -> void* {
        void* pp = ws + off;
        off += (bytes + 255) & ~(size_t)255;
        return pp;
    };
    float* ef    = (float*)alloc((size_t)E_EDGES * FE * sizeof(float));   // 134 MB
    float* p     = (float*)alloc((size_t)E_EDGES * sizeof(float));
    float* z     = (float*)alloc(N_NODES * sizeof(float));
    float* fni   = (float*)alloc(N_NODES * FE * sizeof(float));
    float* fnj   = (float*)alloc(N_NODES * FE * sizeof(float));
    float* h     = (float*)alloc(N_NODES * FC * sizeof(float));
    float* S     = (float*)alloc((size_t)N_NODES * N_NODES * sizeof(float)); // 4 MB
    float* nodeA = (float*)alloc(N_NODES * FC * sizeof(float));

    // node state init
    hipMemcpyAsync(nodeA, node_feature, N_NODES * FC * sizeof(float),
                   hipMemcpyDeviceToDevice, stream);

    for (int l = 0; l < NLAYERS; l++) {
        const float* node_in = nodeA;
        float* node_out = (l == NLAYERS - 1) ? out : nodeA;

        node_kernel<<<N_NODES, 256, 0, stream>>>(
            node_in, W_ni + (size_t)l * FC * FE, W_nj + (size_t)l * FC * FE,
            W_node + (size_t)l * FC * FC, bias_node + (size_t)l * FC,
            fni, fnj, h, z);

        hipMemsetAsync(S, 0, (size_t)N_NODES * N_NODES * sizeof(float), stream);

        if (l == 0) {
            edge_kernel<true><<<2048, 256, 0, stream>>>(
                ef, edge_feature, W_in, b_in, fni, fnj, src, dst,
                W_fij + (size_t)l * FE * FE, attn + (size_t)l * FE, p, z);
        } else {
            edge_kernel<false><<<2048, 256, 0, stream>>>(
                ef, nullptr, nullptr, nullptr, fni, fnj, src, dst,
                W_fij + (size_t)l * FE * FE, attn + (size_t)l * FE, p, z);
        }

        scatter_kernel<<<E_EDGES / 256, 256, 0, stream>>>(p, z, src, dst, S);

        spmm_kernel<<<N_NODES, 256, 0, stream>>>(S, h, node_in, node_out);
    }
}